// Round 5
// baseline (1220.186 us; speedup 1.0000x reference)
//
#include <hip/hip_runtime.h>

#define NNODES 100000
#define NEDGES 1600000
#define DDIM   128
#define SCAN_NB ((NNODES + 1023) / 1024)   // 98
#define NBUK ((NNODES + 127) / 128)        // 782 buckets of 128 nodes

typedef __attribute__((ext_vector_type(8))) short short8;
typedef __attribute__((ext_vector_type(4))) float f32x4;

// f32 -> bf16 round-to-nearest-even (bit trick; NaN irrelevant here)
__device__ __forceinline__ unsigned short f2bf(float f) {
    unsigned u = __float_as_uint(f);
    u += 0x7FFFu + ((u >> 16) & 1u);
    return (unsigned short)(u >> 16);
}

// ---------------- CSR build ----------------

// per-node degree histogram + per-bucket histogram in one edge pass
__global__ void sage_hist2(const int* __restrict__ dst, int* __restrict__ deg,
                           int* __restrict__ bcnt) {
    int i = blockIdx.x * blockDim.x + threadIdx.x;
    if (i < NEDGES) {
        int d = dst[i];
        atomicAdd(&deg[d], 1);
        atomicAdd(&bcnt[d >> 7], 1);
    }
}

// Phase 1: per-block sums over 1024-elem chunks (256 thr x 4)
__global__ void __launch_bounds__(256) sage_scan1(const int* __restrict__ deg,
                                                  int* __restrict__ bsum) {
    int idx0 = blockIdx.x * 1024 + threadIdx.x * 4;
    int local = 0;
    if (idx0 < NNODES) {   // NNODES % 4 == 0 -> full int4 in bounds
        int4 v = *(const int4*)&deg[idx0];
        local = v.x + v.y + v.z + v.w;
    }
    int lane = threadIdx.x & 63, w = threadIdx.x >> 6;
    for (int off = 32; off; off >>= 1) local += __shfl_down(local, off);
    __shared__ int ws[4];
    if (lane == 0) ws[w] = local;
    __syncthreads();
    if (threadIdx.x == 0) bsum[blockIdx.x] = ws[0] + ws[1] + ws[2] + ws[3];
}

// Phase 2: scan the 98 block sums (one small block)
__global__ void __launch_bounds__(128) sage_scan2(const int* __restrict__ bsum,
                                                  int* __restrict__ bofs,
                                                  int* __restrict__ rowptr) {
    __shared__ int sm[128];
    int t = threadIdx.x;
    int v = (t < SCAN_NB) ? bsum[t] : 0;
    sm[t] = v;
    __syncthreads();
    for (int off = 1; off < 128; off <<= 1) {
        int u = (t >= off) ? sm[t - off] : 0;
        __syncthreads();
        sm[t] += u;
        __syncthreads();
    }
    if (t < SCAN_NB) bofs[t] = sm[t] - v;            // exclusive block offset
    if (t == SCAN_NB - 1) rowptr[NNODES] = sm[t];    // total edge count
}

// Phase 3: block-local exclusive scan + block offset -> rowptr
__global__ void __launch_bounds__(256) sage_scan3(const int* __restrict__ deg,
                                                  const int* __restrict__ bofs,
                                                  int* __restrict__ rowptr) {
    int idx0 = blockIdx.x * 1024 + threadIdx.x * 4;
    int4 v = {0, 0, 0, 0};
    if (idx0 < NNODES) v = *(const int4*)&deg[idx0];
    int local = v.x + v.y + v.z + v.w;
    int lane = threadIdx.x & 63, w = threadIdx.x >> 6;
    int sc = local;
    for (int off = 1; off < 64; off <<= 1) {
        int u = __shfl_up(sc, off);
        if (lane >= off) sc += u;
    }
    __shared__ int ws[4];
    if (lane == 63) ws[w] = sc;
    __syncthreads();
    int wofs = 0;
    for (int i = 0; i < 4; ++i) if (i < w) wofs += ws[i];
    int excl = bofs[blockIdx.x] + wofs + sc - local;
    if (idx0 < NNODES) {
        rowptr[idx0]     = excl;
        rowptr[idx0 + 1] = excl + v.x;
        rowptr[idx0 + 2] = excl + v.x + v.y;
        rowptr[idx0 + 3] = excl + v.x + v.y + v.z;
    }
}

// scan the 782 bucket counts (single 1024-thread block, Hillis-Steele)
__global__ void __launch_bounds__(1024) sage_bscan(const int* __restrict__ bcnt,
                                                   int* __restrict__ bofs2) {
    __shared__ int sm[1024];
    int t = threadIdx.x;
    int v = (t < NBUK) ? bcnt[t] : 0;
    sm[t] = v;
    __syncthreads();
    for (int off = 1; off < 1024; off <<= 1) {
        int u = (t >= off) ? sm[t - off] : 0;
        __syncthreads();
        sm[t] += u;
        __syncthreads();
    }
    if (t < NBUK) bofs2[t] = sm[t] - v;   // exclusive
}

// bucket-scatter: pack (dst&127)<<17 | src into bucket-grouped ebuf
__global__ void sage_bucket(const int* __restrict__ src, const int* __restrict__ dst,
                            const int* __restrict__ bofs2, int* __restrict__ bfill,
                            unsigned* __restrict__ ebuf) {
    int i = blockIdx.x * blockDim.x + threadIdx.x;
    if (i < NEDGES) {
        int d = dst[i];
        int b = d >> 7;
        int p = bofs2[b] + atomicAdd(&bfill[b], 1);
        ebuf[p] = ((unsigned)(d & 127) << 17) | (unsigned)src[i];
    }
}

// final scatter: one block per bucket; writes land in the bucket's small rowptr window
__global__ void __launch_bounds__(256) sage_scatter2(const unsigned* __restrict__ ebuf,
                                                     const int* __restrict__ bofs2,
                                                     const int* __restrict__ rowptr,
                                                     int* __restrict__ fill,
                                                     int* __restrict__ sorted) {
    int b = blockIdx.x;
    int s = bofs2[b];
    int e = (b == NBUK - 1) ? NEDGES : bofs2[b + 1];
    int base = b << 7;
    for (int i = s + threadIdx.x; i < e; i += 256) {
        unsigned v = ebuf[i];
        int srcn = (int)(v & 0x1FFFFu);
        int d = base + (int)(v >> 17);
        int pos = rowptr[d] + atomicAdd(&fill[d], 1);
        sorted[pos] = srcn;
    }
}

// ---------------- dtype prep ----------------

// f32 -> bf16, 4 elems/thread
__global__ void sage_cvt(const float* __restrict__ in, unsigned short* __restrict__ out, int n) {
    int i = (blockIdx.x * blockDim.x + threadIdx.x) * 4;
    if (i < n) {
        float4 v = *(const float4*)&in[i];
        uint2 o;
        o.x = (unsigned)f2bf(v.x) | ((unsigned)f2bf(v.y) << 16);
        o.y = (unsigned)f2bf(v.z) | ((unsigned)f2bf(v.w) << 16);
        *(uint2*)&out[i] = o;
    }
}

// Wcat[j][k] = (k<128 ? Wl[j][k] : Wr[j][k-128]) as bf16;  [128][256]
__global__ void sage_wprep(const float* __restrict__ Wl, const float* __restrict__ Wr,
                           unsigned short* __restrict__ Wcat) {
    int idx = blockIdx.x * blockDim.x + threadIdx.x;  // 0..32767
    int j = idx >> 8, k = idx & 255;
    float v = (k < 128) ? Wl[j * 128 + k] : Wr[j * 128 + (k - 128)];
    Wcat[idx] = f2bf(v);
}

// ---------------- aggregation (one wave per node) ----------------
// in: [N][128] bf16.  ag: [N][128] bf16 = mean over neighbors (0 if none)

__global__ void __launch_bounds__(256) sage_aggr(const unsigned short* __restrict__ in,
                                                 const int* __restrict__ rowptr,
                                                 const int* __restrict__ srcs,
                                                 unsigned short* __restrict__ ag) {
    int node = blockIdx.x * 4 + (threadIdx.x >> 6);
    if (node >= NNODES) return;
    int lane = threadIdx.x & 63;
    int beg = rowptr[node], end = rowptr[node + 1];
    const unsigned* inu = (const unsigned*)in;   // 64 uints per row
    float s0 = 0.f, s1 = 0.f;
    int i = beg;
    for (; i + 4 <= end; i += 4) {
        int n0 = srcs[i], n1 = srcs[i + 1], n2 = srcs[i + 2], n3 = srcs[i + 3];
        unsigned v0 = inu[n0 * 64 + lane];
        unsigned v1 = inu[n1 * 64 + lane];
        unsigned v2 = inu[n2 * 64 + lane];
        unsigned v3 = inu[n3 * 64 + lane];
        s0 += __uint_as_float(v0 << 16);
        s1 += __uint_as_float(v0 & 0xFFFF0000u);
        s0 += __uint_as_float(v1 << 16);
        s1 += __uint_as_float(v1 & 0xFFFF0000u);
        s0 += __uint_as_float(v2 << 16);
        s1 += __uint_as_float(v2 & 0xFFFF0000u);
        s0 += __uint_as_float(v3 << 16);
        s1 += __uint_as_float(v3 & 0xFFFF0000u);
    }
    for (; i < end; ++i) {
        unsigned v = inu[srcs[i] * 64 + lane];
        s0 += __uint_as_float(v << 16);
        s1 += __uint_as_float(v & 0xFFFF0000u);
    }
    int cnt = end - beg;
    float inv = (cnt > 0) ? 1.0f / (float)cnt : 0.0f;
    s0 *= inv; s1 *= inv;
    unsigned* agu = (unsigned*)ag;               // 64 uints per row
    agu[node * 64 + lane] = (unsigned)f2bf(s0) | ((unsigned)f2bf(s1) << 16);
}

// ---------------- GEMM: out[i][j] = sum_k Acat[i][k]*W[j][k] + bias[j] ----------------

template <int EPI>
__global__ void __launch_bounds__(256) sage_gemm(const unsigned short* __restrict__ A0,
                                                 const unsigned short* __restrict__ A1,
                                                 const unsigned short* __restrict__ W,
                                                 const float* __restrict__ bias,
                                                 void* __restrict__ outp) {
    __shared__ unsigned short As[128 * 64];
    __shared__ unsigned short Bs[128 * 64];
    const int tid = threadIdx.x;
    const int bm = blockIdx.x * 128;

    f32x4 acc[4][4];
    const f32x4 zero = {0.f, 0.f, 0.f, 0.f};
    for (int m = 0; m < 4; ++m)
        for (int n = 0; n < 4; ++n) acc[m][n] = zero;

    const int lane = tid & 63, wid = tid >> 6;
    const int wr = wid >> 1, wc = wid & 1;
    const int l16 = lane & 15, lhi = lane >> 4;

    for (int kt = 0; kt < 256; kt += 64) {
        const unsigned short* Asrc = (kt < 128) ? A0 : A1;
        const int kofs = kt & 127;
        __syncthreads();
        #pragma unroll
        for (int it = 0; it < 4; ++it) {
            int idx = it * 2048 + tid * 8;
            int r = idx >> 6, k = idx & 63;
            int row = bm + r; if (row >= NNODES) row = NNODES - 1;
            *(int4*)&As[idx] = *(const int4*)&Asrc[row * 128 + kofs + k];
            *(int4*)&Bs[idx] = *(const int4*)&W[r * 256 + kt + k];
        }
        __syncthreads();
        #pragma unroll
        for (int kk = 0; kk < 64; kk += 32) {
            short8 af[4], bf[4];
            #pragma unroll
            for (int m = 0; m < 4; ++m)
                af[m] = *(const short8*)&As[(wr * 64 + m * 16 + l16) * 64 + kk + lhi * 8];
            #pragma unroll
            for (int n = 0; n < 4; ++n)
                bf[n] = *(const short8*)&Bs[(wc * 64 + n * 16 + l16) * 64 + kk + lhi * 8];
            #pragma unroll
            for (int m = 0; m < 4; ++m)
                #pragma unroll
                for (int n = 0; n < 4; ++n)
                    acc[m][n] = __builtin_amdgcn_mfma_f32_16x16x32_bf16(af[m], bf[n], acc[m][n], 0, 0, 0);
        }
    }

    for (int n = 0; n < 4; ++n) {
        int col = wc * 64 + n * 16 + l16;
        float bv = bias[col];
        for (int m = 0; m < 4; ++m) {
            int row0 = bm + wr * 64 + m * 16 + lhi * 4;
            #pragma unroll
            for (int v = 0; v < 4; ++v) {
                int row = row0 + v;
                if (row < NNODES) {
                    float val = acc[m][n][v] + bv;
                    if (EPI == 0) {
                        val = fmaxf(val, 0.0f);
                        ((unsigned short*)outp)[row * 128 + col] = f2bf(val);
                    } else {
                        ((float*)outp)[row * 128 + col] = val;
                    }
                }
            }
        }
    }
}

// ---------------- row L2 normalize in place (one wave per row) ----------------

__global__ void __launch_bounds__(256) sage_norm(float* __restrict__ out) {
    int node = blockIdx.x * 4 + (threadIdx.x >> 6);
    if (node >= NNODES) return;
    int lane = threadIdx.x & 63;
    float2 v = *(float2*)&out[node * 128 + lane * 2];
    float s = v.x * v.x + v.y * v.y;
    for (int off = 32; off; off >>= 1) s += __shfl_xor(s, off);
    float scale = 1.0f / fmaxf(sqrtf(s), 1e-12f);
    v.x *= scale; v.y *= scale;
    *(float2*)&out[node * 128 + lane * 2] = v;
}

// ---------------- launch ----------------

extern "C" void kernel_launch(void* const* d_in, const int* in_sizes, int n_in,
                              void* d_out, int out_size, void* d_ws, size_t ws_size,
                              hipStream_t stream) {
    const float* x   = (const float*)d_in[0];
    const int* ei    = (const int*)d_in[1];
    const float* W1l = (const float*)d_in[2];
    const float* b1  = (const float*)d_in[3];
    const float* W1r = (const float*)d_in[4];
    const float* W2l = (const float*)d_in[5];
    const float* b2  = (const float*)d_in[6];
    const float* W2r = (const float*)d_in[7];
    const int* srcp = ei;
    const int* dstp = ei + NEDGES;

    char* ws = (char*)d_ws;
    size_t off = 0;
    auto alloc = [&](size_t bytes) -> void* {
        void* p = ws + off;
        off += (bytes + 255) & ~(size_t)255;
        return p;
    };
    // deg/bcnt/bfill contiguous so one memset zeroes all three
    char* zbase = ws;
    int* deg    = (int*)alloc((size_t)NNODES * 4);          // reused as fill
    int* bcnt   = (int*)alloc((size_t)NBUK * 4);
    int* bfill  = (int*)alloc((size_t)NBUK * 4);
    size_t zspan = off;
    int* rowptr = (int*)alloc((size_t)(NNODES + 1) * 4);
    int* bofs2  = (int*)alloc((size_t)NBUK * 4);
    int* sorted = (int*)alloc((size_t)NEDGES * 4);
    unsigned* ebuf = (unsigned*)alloc((size_t)NEDGES * 4);
    int* bsum   = (int*)alloc((size_t)SCAN_NB * 4);
    int* bofs   = (int*)alloc((size_t)SCAN_NB * 4);
    unsigned short* xb = (unsigned short*)alloc((size_t)NNODES * DDIM * 2);
    unsigned short* ag = (unsigned short*)alloc((size_t)NNODES * DDIM * 2);
    unsigned short* wc1 = (unsigned short*)alloc(128 * 256 * 2);
    unsigned short* wc2 = (unsigned short*)alloc(128 * 256 * 2);
    unsigned short* hb = xb;  // layer-1 output overwrites xb in place

    // CSR build (bucketed for write locality)
    hipMemsetAsync(zbase, 0, zspan, stream);
    sage_hist2<<<(NEDGES + 255) / 256, 256, 0, stream>>>(dstp, deg, bcnt);
    sage_scan1<<<SCAN_NB, 256, 0, stream>>>(deg, bsum);
    sage_scan2<<<1, 128, 0, stream>>>(bsum, bofs, rowptr);
    sage_scan3<<<SCAN_NB, 256, 0, stream>>>(deg, bofs, rowptr);
    sage_bscan<<<1, 1024, 0, stream>>>(bcnt, bofs2);
    sage_bucket<<<(NEDGES + 255) / 256, 256, 0, stream>>>(srcp, dstp, bofs2, bfill, ebuf);
    hipMemsetAsync(deg, 0, (size_t)NNODES * 4, stream);  // deg -> fill
    sage_scatter2<<<NBUK, 256, 0, stream>>>(ebuf, bofs2, rowptr, deg, sorted);

    // dtype prep
    sage_cvt<<<(NNODES * DDIM / 4 + 255) / 256, 256, 0, stream>>>(x, xb, NNODES * DDIM);
    sage_wprep<<<128, 256, 0, stream>>>(W1l, W1r, wc1);
    sage_wprep<<<128, 256, 0, stream>>>(W2l, W2r, wc2);

    const int aggr_grid = (NNODES + 3) / 4;
    const int gemm_grid = (NNODES + 127) / 128;

    // layer 1: h = relu(aggr@W1l.T + b1 + x@W1r.T)   (bf16, in place over xb)
    sage_aggr<<<aggr_grid, 256, 0, stream>>>(xb, rowptr, sorted, ag);
    sage_gemm<0><<<gemm_grid, 256, 0, stream>>>(ag, xb, wc1, b1, (void*)hb);
    // layer 2: out = aggr@W2l.T + b2 + h@W2r.T       (f32)
    sage_aggr<<<aggr_grid, 256, 0, stream>>>(hb, rowptr, sorted, ag);
    sage_gemm<1><<<gemm_grid, 256, 0, stream>>>(ag, hb, wc2, b2, d_out);
    // normalize rows
    sage_norm<<<aggr_grid, 256, 0, stream>>>((float*)d_out);
}

// Round 7
// 413.387 us; speedup vs baseline: 2.9517x; 2.9517x over previous
//
#include <hip/hip_runtime.h>

#define NNODES 100000
#define NEDGES 1600000
#define DDIM   128
#define NBUK ((NNODES + 127) / 128)        // 782 buckets of 128 nodes
#define EB   4096                          // edges per sort block
#define NBLK_E ((NEDGES + EB - 1) / EB)    // 391

typedef __attribute__((ext_vector_type(8))) short short8;
typedef __attribute__((ext_vector_type(4))) float f32x4;

// f32 -> bf16 round-to-nearest-even (bit trick; NaN irrelevant here)
__device__ __forceinline__ unsigned short f2bf(float f) {
    unsigned u = __float_as_uint(f);
    u += 0x7FFFu + ((u >> 16) & 1u);
    return (unsigned short)(u >> 16);
}

// ---------------- CSR build: deterministic bucketed counting sort ----------------
// No per-edge GLOBAL atomics anywhere (round-5 lesson: 1.6M atomics / 782 addrs
// serialize at ~210ns per same-line RMW = 431us). All per-edge atomics are LDS.

// P1: per-block LDS histogram over buckets -> histmat[blk][NBUK] (coalesced)
__global__ void __launch_bounds__(256) p1_hist(const int* __restrict__ dst,
                                               int* __restrict__ histmat) {
    __shared__ int h[NBUK];
    for (int i = threadIdx.x; i < NBUK; i += 256) h[i] = 0;
    __syncthreads();
    int base = blockIdx.x * EB;
    int end = base + EB; if (end > NEDGES) end = NEDGES;
    for (int i = base + threadIdx.x; i < end; i += 256)
        atomicAdd(&h[dst[i] >> 7], 1);
    __syncthreads();
    for (int i = threadIdx.x; i < NBUK; i += 256)
        histmat[blockIdx.x * NBUK + i] = h[i];
}

// P2a: per-bucket exclusive scan down the block axis -> colofs + totals
__global__ void __launch_bounds__(256) p2_colscan(const int* __restrict__ histmat,
                                                  int* __restrict__ colofs,
                                                  int* __restrict__ totals) {
    int b = blockIdx.x * 4 + (threadIdx.x >> 6);
    if (b >= NBUK) return;
    int lane = threadIdx.x & 63;
    int running = 0;
    #pragma unroll
    for (int r = 0; r < (NBLK_E + 63) / 64; ++r) {
        int blk = r * 64 + lane;
        int v = (blk < NBLK_E) ? histmat[blk * NBUK + b] : 0;
        int sc = v;
        for (int o = 1; o < 64; o <<= 1) {
            int u = __shfl_up(sc, o);
            if (lane >= o) sc += u;
        }
        if (blk < NBLK_E) colofs[blk * NBUK + b] = running + sc - v;
        running += __shfl(sc, 63);
    }
    if (lane == 0) totals[b] = running;
}

// P2b: scan bucket totals -> bbase[0..NBUK]; also rowptr[NNODES]
__global__ void __launch_bounds__(1024) p2b_bscan(const int* __restrict__ totals,
                                                  int* __restrict__ bbase,
                                                  int* __restrict__ rowptr) {
    __shared__ int sm[1024];
    int t = threadIdx.x;
    int v = (t < NBUK) ? totals[t] : 0;
    sm[t] = v;
    __syncthreads();
    for (int o = 1; o < 1024; o <<= 1) {
        int u = (t >= o) ? sm[t - o] : 0;
        __syncthreads();
        sm[t] += u;
        __syncthreads();
    }
    if (t < NBUK) bbase[t] = sm[t] - v;
    if (t == 0) { bbase[NBUK] = NEDGES; rowptr[NNODES] = NEDGES; }
}

// P3: deterministic bucket-grouped scatter via LDS cursors (init bbase+colofs)
__global__ void __launch_bounds__(256) p3_bucket(const int* __restrict__ src,
                                                 const int* __restrict__ dst,
                                                 const int* __restrict__ colofs,
                                                 const int* __restrict__ bbase,
                                                 unsigned* __restrict__ ebuf) {
    __shared__ int cur[NBUK];
    for (int i = threadIdx.x; i < NBUK; i += 256)
        cur[i] = bbase[i] + colofs[blockIdx.x * NBUK + i];
    __syncthreads();
    int base = blockIdx.x * EB;
    int end = base + EB; if (end > NEDGES) end = NEDGES;
    for (int i = base + threadIdx.x; i < end; i += 256) {
        int d = dst[i];
        int pos = atomicAdd(&cur[d >> 7], 1);
        ebuf[pos] = ((unsigned)(d & 127) << 17) | (unsigned)src[i];
    }
}

// P4: one block per bucket: per-node LDS count+scan -> rowptr (coalesced) and
// sorted[] (writes confined to the bucket's ~8KB window -> full-line writebacks)
__global__ void __launch_bounds__(256) p4_final(const unsigned* __restrict__ ebuf,
                                                const int* __restrict__ bbase,
                                                int* __restrict__ rowptr,
                                                int* __restrict__ sorted) {
    __shared__ int cnt[128];
    __shared__ int ofs[128];
    int b = blockIdx.x;
    int s = bbase[b], e = bbase[b + 1];
    int t = threadIdx.x;
    if (t < 128) cnt[t] = 0;
    __syncthreads();
    for (int i = s + t; i < e; i += 256)
        atomicAdd(&cnt[ebuf[i] >> 17], 1);
    __syncthreads();
    if (t < 128) ofs[t] = cnt[t];
    __syncthreads();
    for (int o = 1; o < 128; o <<= 1) {
        int u = (t >= o && t < 128) ? ofs[t - o] : 0;
        __syncthreads();
        if (t < 128) ofs[t] += u;
        __syncthreads();
    }
    int nodebase = b << 7;
    if (t < 128) {
        int excl = ofs[t] - cnt[t];
        if (nodebase + t < NNODES) rowptr[nodebase + t] = s + excl;
        cnt[t] = excl;  // reuse as cursor
    }
    __syncthreads();
    for (int i = s + t; i < e; i += 256) {
        unsigned v = ebuf[i];
        int r = atomicAdd(&cnt[v >> 17], 1);
        sorted[s + r] = (int)(v & 0x1FFFFu);
    }
}

// ---------------- dtype prep ----------------

__global__ void sage_cvt(const float* __restrict__ in, unsigned short* __restrict__ out, int n) {
    int i = (blockIdx.x * blockDim.x + threadIdx.x) * 4;
    if (i < n) {
        float4 v = *(const float4*)&in[i];
        uint2 o;
        o.x = (unsigned)f2bf(v.x) | ((unsigned)f2bf(v.y) << 16);
        o.y = (unsigned)f2bf(v.z) | ((unsigned)f2bf(v.w) << 16);
        *(uint2*)&out[i] = o;
    }
}

// Wcat[j][k] = (k<128 ? Wl[j][k] : Wr[j][k-128]) as bf16;  [128][256]
__global__ void sage_wprep(const float* __restrict__ Wl, const float* __restrict__ Wr,
                           unsigned short* __restrict__ Wcat) {
    int idx = blockIdx.x * blockDim.x + threadIdx.x;  // 0..32767
    int j = idx >> 8, k = idx & 255;
    float v = (k < 128) ? Wl[j * 128 + k] : Wr[j * 128 + (k - 128)];
    Wcat[idx] = f2bf(v);
}

// ---------------- aggregation (one wave per node) ----------------
// in: [N][128] bf16.  ag: [N][128] bf16 = mean over neighbors (0 if none)

__global__ void __launch_bounds__(256) sage_aggr(const unsigned short* __restrict__ in,
                                                 const int* __restrict__ rowptr,
                                                 const int* __restrict__ srcs,
                                                 unsigned short* __restrict__ ag) {
    int node = blockIdx.x * 4 + (threadIdx.x >> 6);
    if (node >= NNODES) return;
    int lane = threadIdx.x & 63;
    int beg = rowptr[node], end = rowptr[node + 1];
    const unsigned* inu = (const unsigned*)in;   // 64 uints per row
    float s0 = 0.f, s1 = 0.f;
    int i = beg;
    for (; i + 4 <= end; i += 4) {
        int n0 = srcs[i], n1 = srcs[i + 1], n2 = srcs[i + 2], n3 = srcs[i + 3];
        unsigned v0 = inu[n0 * 64 + lane];
        unsigned v1 = inu[n1 * 64 + lane];
        unsigned v2 = inu[n2 * 64 + lane];
        unsigned v3 = inu[n3 * 64 + lane];
        s0 += __uint_as_float(v0 << 16);
        s1 += __uint_as_float(v0 & 0xFFFF0000u);
        s0 += __uint_as_float(v1 << 16);
        s1 += __uint_as_float(v1 & 0xFFFF0000u);
        s0 += __uint_as_float(v2 << 16);
        s1 += __uint_as_float(v2 & 0xFFFF0000u);
        s0 += __uint_as_float(v3 << 16);
        s1 += __uint_as_float(v3 & 0xFFFF0000u);
    }
    for (; i < end; ++i) {
        unsigned v = inu[srcs[i] * 64 + lane];
        s0 += __uint_as_float(v << 16);
        s1 += __uint_as_float(v & 0xFFFF0000u);
    }
    int cnt = end - beg;
    float inv = (cnt > 0) ? 1.0f / (float)cnt : 0.0f;
    s0 *= inv; s1 *= inv;
    unsigned* agu = (unsigned*)ag;               // 64 uints per row
    agu[node * 64 + lane] = (unsigned)f2bf(s0) | ((unsigned)f2bf(s1) << 16);
}

// ---------------- GEMM: out[i][j] = sum_k Acat[i][k]*W[j][k] + bias[j] ----------------

template <int EPI>
__global__ void __launch_bounds__(256) sage_gemm(const unsigned short* __restrict__ A0,
                                                 const unsigned short* __restrict__ A1,
                                                 const unsigned short* __restrict__ W,
                                                 const float* __restrict__ bias,
                                                 void* __restrict__ outp) {
    __shared__ unsigned short As[128 * 64];
    __shared__ unsigned short Bs[128 * 64];
    const int tid = threadIdx.x;
    const int bm = blockIdx.x * 128;

    f32x4 acc[4][4];
    const f32x4 zero = {0.f, 0.f, 0.f, 0.f};
    for (int m = 0; m < 4; ++m)
        for (int n = 0; n < 4; ++n) acc[m][n] = zero;

    const int lane = tid & 63, wid = tid >> 6;
    const int wr = wid >> 1, wc = wid & 1;
    const int l16 = lane & 15, lhi = lane >> 4;

    for (int kt = 0; kt < 256; kt += 64) {
        const unsigned short* Asrc = (kt < 128) ? A0 : A1;
        const int kofs = kt & 127;
        __syncthreads();
        #pragma unroll
        for (int it = 0; it < 4; ++it) {
            int idx = it * 2048 + tid * 8;
            int r = idx >> 6, k = idx & 63;
            int row = bm + r; if (row >= NNODES) row = NNODES - 1;
            *(int4*)&As[idx] = *(const int4*)&Asrc[row * 128 + kofs + k];
            *(int4*)&Bs[idx] = *(const int4*)&W[r * 256 + kt + k];
        }
        __syncthreads();
        #pragma unroll
        for (int kk = 0; kk < 64; kk += 32) {
            short8 af[4], bf[4];
            #pragma unroll
            for (int m = 0; m < 4; ++m)
                af[m] = *(const short8*)&As[(wr * 64 + m * 16 + l16) * 64 + kk + lhi * 8];
            #pragma unroll
            for (int n = 0; n < 4; ++n)
                bf[n] = *(const short8*)&Bs[(wc * 64 + n * 16 + l16) * 64 + kk + lhi * 8];
            #pragma unroll
            for (int m = 0; m < 4; ++m)
                #pragma unroll
                for (int n = 0; n < 4; ++n)
                    acc[m][n] = __builtin_amdgcn_mfma_f32_16x16x32_bf16(af[m], bf[n], acc[m][n], 0, 0, 0);
        }
    }

    for (int n = 0; n < 4; ++n) {
        int col = wc * 64 + n * 16 + l16;
        float bv = bias[col];
        for (int m = 0; m < 4; ++m) {
            int row0 = bm + wr * 64 + m * 16 + lhi * 4;
            #pragma unroll
            for (int v = 0; v < 4; ++v) {
                int row = row0 + v;
                if (row < NNODES) {
                    float val = acc[m][n][v] + bv;
                    if (EPI == 0) {
                        val = fmaxf(val, 0.0f);
                        ((unsigned short*)outp)[row * 128 + col] = f2bf(val);
                    } else {
                        ((float*)outp)[row * 128 + col] = val;
                    }
                }
            }
        }
    }
}

// ---------------- row L2 normalize in place (one wave per row) ----------------

__global__ void __launch_bounds__(256) sage_norm(float* __restrict__ out) {
    int node = blockIdx.x * 4 + (threadIdx.x >> 6);
    if (node >= NNODES) return;
    int lane = threadIdx.x & 63;
    float2 v = *(float2*)&out[node * 128 + lane * 2];
    float s = v.x * v.x + v.y * v.y;
    for (int off = 32; off; off >>= 1) s += __shfl_xor(s, off);
    float scale = 1.0f / fmaxf(sqrtf(s), 1e-12f);
    v.x *= scale; v.y *= scale;
    *(float2*)&out[node * 128 + lane * 2] = v;
}

// ---------------- launch ----------------

extern "C" void kernel_launch(void* const* d_in, const int* in_sizes, int n_in,
                              void* d_out, int out_size, void* d_ws, size_t ws_size,
                              hipStream_t stream) {
    const float* x   = (const float*)d_in[0];
    const int* ei    = (const int*)d_in[1];
    const float* W1l = (const float*)d_in[2];
    const float* b1  = (const float*)d_in[3];
    const float* W1r = (const float*)d_in[4];
    const float* W2l = (const float*)d_in[5];
    const float* b2  = (const float*)d_in[6];
    const float* W2r = (const float*)d_in[7];
    const int* srcp = ei;
    const int* dstp = ei + NEDGES;

    char* ws = (char*)d_ws;
    size_t off = 0;
    auto alloc = [&](size_t bytes) -> void* {
        void* p = ws + off;
        off += (bytes + 255) & ~(size_t)255;
        return p;
    };
    int* histmat = (int*)alloc((size_t)NBLK_E * NBUK * 4);   // 1.22 MB
    int* colofs  = (int*)alloc((size_t)NBLK_E * NBUK * 4);   // 1.22 MB
    int* totals  = (int*)alloc((size_t)NBUK * 4);
    int* bbase   = (int*)alloc((size_t)(NBUK + 1) * 4);
    int* rowptr  = (int*)alloc((size_t)(NNODES + 1) * 4);
    int* sorted  = (int*)alloc((size_t)NEDGES * 4);
    unsigned* ebuf = (unsigned*)alloc((size_t)NEDGES * 4);
    unsigned short* xb = (unsigned short*)alloc((size_t)NNODES * DDIM * 2);
    unsigned short* ag = (unsigned short*)alloc((size_t)NNODES * DDIM * 2);
    unsigned short* wc1 = (unsigned short*)alloc(128 * 256 * 2);
    unsigned short* wc2 = (unsigned short*)alloc(128 * 256 * 2);
    unsigned short* hb = xb;  // layer-1 output overwrites xb in place

    // CSR build: deterministic counting sort, zero per-edge global atomics
    p1_hist<<<NBLK_E, 256, 0, stream>>>(dstp, histmat);
    p2_colscan<<<(NBUK + 3) / 4, 256, 0, stream>>>(histmat, colofs, totals);
    p2b_bscan<<<1, 1024, 0, stream>>>(totals, bbase, rowptr);
    p3_bucket<<<NBLK_E, 256, 0, stream>>>(srcp, dstp, colofs, bbase, ebuf);
    p4_final<<<NBUK, 256, 0, stream>>>(ebuf, bbase, rowptr, sorted);

    // dtype prep
    sage_cvt<<<(NNODES * DDIM / 4 + 255) / 256, 256, 0, stream>>>(x, xb, NNODES * DDIM);
    sage_wprep<<<128, 256, 0, stream>>>(W1l, W1r, wc1);
    sage_wprep<<<128, 256, 0, stream>>>(W2l, W2r, wc2);

    const int aggr_grid = (NNODES + 3) / 4;
    const int gemm_grid = (NNODES + 127) / 128;

    // layer 1: h = relu(aggr@W1l.T + b1 + x@W1r.T)   (bf16, in place over xb)
    sage_aggr<<<aggr_grid, 256, 0, stream>>>(xb, rowptr, sorted, ag);
    sage_gemm<0><<<gemm_grid, 256, 0, stream>>>(ag, xb, wc1, b1, (void*)hb);
    // layer 2: out = aggr@W2l.T + b2 + h@W2r.T       (f32)
    sage_aggr<<<aggr_grid, 256, 0, stream>>>(hb, rowptr, sorted, ag);
    sage_gemm<1><<<gemm_grid, 256, 0, stream>>>(ag, hb, wc2, b2, d_out);
    // normalize rows
    sage_norm<<<aggr_grid, 256, 0, stream>>>((float*)d_out);
}

// Round 8
// 389.287 us; speedup vs baseline: 3.1344x; 1.0619x over previous
//
#include <hip/hip_runtime.h>

#define NNODES 100000
#define NEDGES 1600000
#define DDIM   128
#define NBUK ((NNODES + 127) / 128)        // 782 buckets of 128 nodes
#define EB   8192                          // edges per sort block
#define NBLK_E ((NEDGES + EB - 1) / EB)    // 196

typedef __attribute__((ext_vector_type(8))) short short8;
typedef __attribute__((ext_vector_type(4))) float f32x4;

// f32 -> bf16 round-to-nearest-even (bit trick; NaN irrelevant here)
__device__ __forceinline__ unsigned short f2bf(float f) {
    unsigned u = __float_as_uint(f);
    u += 0x7FFFu + ((u >> 16) & 1u);
    return (unsigned short)(u >> 16);
}

// ---------------- CSR build: deterministic bucketed counting sort ----------------
// No per-edge GLOBAL atomics anywhere (round-5 lesson: 1.6M atomics / 782 addrs
// serialize at ~210ns per same-line RMW = 431us). All per-edge atomics are LDS.

// P1: per-block LDS histogram over buckets -> histmat[blk][NBUK] (coalesced)
__global__ void __launch_bounds__(256) p1_hist(const int* __restrict__ dst,
                                               int* __restrict__ histmat) {
    __shared__ int h[NBUK];
    for (int i = threadIdx.x; i < NBUK; i += 256) h[i] = 0;
    __syncthreads();
    int base = blockIdx.x * EB;
    int end = base + EB; if (end > NEDGES) end = NEDGES;
    for (int i = base + threadIdx.x; i < end; i += 256)
        atomicAdd(&h[dst[i] >> 7], 1);
    __syncthreads();
    for (int i = threadIdx.x; i < NBUK; i += 256)
        histmat[blockIdx.x * NBUK + i] = h[i];
}

// P2a: per-bucket exclusive scan down the block axis -> colofs + totals
__global__ void __launch_bounds__(256) p2_colscan(const int* __restrict__ histmat,
                                                  int* __restrict__ colofs,
                                                  int* __restrict__ totals) {
    int b = blockIdx.x * 4 + (threadIdx.x >> 6);
    if (b >= NBUK) return;
    int lane = threadIdx.x & 63;
    int running = 0;
    #pragma unroll
    for (int r = 0; r < (NBLK_E + 63) / 64; ++r) {
        int blk = r * 64 + lane;
        int v = (blk < NBLK_E) ? histmat[blk * NBUK + b] : 0;
        int sc = v;
        for (int o = 1; o < 64; o <<= 1) {
            int u = __shfl_up(sc, o);
            if (lane >= o) sc += u;
        }
        if (blk < NBLK_E) colofs[blk * NBUK + b] = running + sc - v;
        running += __shfl(sc, 63);
    }
    if (lane == 0) totals[b] = running;
}

// P2b: scan bucket totals -> bbase[0..NBUK]; also rowptr[NNODES]
__global__ void __launch_bounds__(1024) p2b_bscan(const int* __restrict__ totals,
                                                  int* __restrict__ bbase,
                                                  int* __restrict__ rowptr) {
    __shared__ int sm[1024];
    int t = threadIdx.x;
    int v = (t < NBUK) ? totals[t] : 0;
    sm[t] = v;
    __syncthreads();
    for (int o = 1; o < 1024; o <<= 1) {
        int u = (t >= o) ? sm[t - o] : 0;
        __syncthreads();
        sm[t] += u;
        __syncthreads();
    }
    if (t < NBUK) bbase[t] = sm[t] - v;
    if (t == 0) { bbase[NBUK] = NEDGES; rowptr[NNODES] = NEDGES; }
}

// P3: deterministic bucket-grouped scatter via LDS cursors (init bbase+colofs)
__global__ void __launch_bounds__(256) p3_bucket(const int* __restrict__ src,
                                                 const int* __restrict__ dst,
                                                 const int* __restrict__ colofs,
                                                 const int* __restrict__ bbase,
                                                 unsigned* __restrict__ ebuf) {
    __shared__ int cur[NBUK];
    for (int i = threadIdx.x; i < NBUK; i += 256)
        cur[i] = bbase[i] + colofs[blockIdx.x * NBUK + i];
    __syncthreads();
    int base = blockIdx.x * EB;
    int end = base + EB; if (end > NEDGES) end = NEDGES;
    for (int i = base + threadIdx.x; i < end; i += 256) {
        int d = dst[i];
        int pos = atomicAdd(&cur[d >> 7], 1);
        ebuf[pos] = ((unsigned)(d & 127) << 17) | (unsigned)src[i];
    }
}

// P4: one block per bucket: per-node LDS count+scan -> rowptr (coalesced) and
// sorted[] (writes confined to the bucket's ~8KB window -> full-line writebacks)
__global__ void __launch_bounds__(256) p4_final(const unsigned* __restrict__ ebuf,
                                                const int* __restrict__ bbase,
                                                int* __restrict__ rowptr,
                                                int* __restrict__ sorted) {
    __shared__ int cnt[128];
    __shared__ int ofs[128];
    int b = blockIdx.x;
    int s = bbase[b], e = bbase[b + 1];
    int t = threadIdx.x;
    if (t < 128) cnt[t] = 0;
    __syncthreads();
    for (int i = s + t; i < e; i += 256)
        atomicAdd(&cnt[ebuf[i] >> 17], 1);
    __syncthreads();
    if (t < 128) ofs[t] = cnt[t];
    __syncthreads();
    for (int o = 1; o < 128; o <<= 1) {
        int u = (t >= o && t < 128) ? ofs[t - o] : 0;
        __syncthreads();
        if (t < 128) ofs[t] += u;
        __syncthreads();
    }
    int nodebase = b << 7;
    if (t < 128) {
        int excl = ofs[t] - cnt[t];
        if (nodebase + t < NNODES) rowptr[nodebase + t] = s + excl;
        cnt[t] = excl;  // reuse as cursor
    }
    __syncthreads();
    for (int i = s + t; i < e; i += 256) {
        unsigned v = ebuf[i];
        int r = atomicAdd(&cnt[v >> 17], 1);
        sorted[s + r] = (int)(v & 0x1FFFFu);
    }
}

// ---------------- dtype prep ----------------

__global__ void sage_cvt(const float* __restrict__ in, unsigned short* __restrict__ out, int n) {
    int i = (blockIdx.x * blockDim.x + threadIdx.x) * 4;
    if (i < n) {
        float4 v = *(const float4*)&in[i];
        uint2 o;
        o.x = (unsigned)f2bf(v.x) | ((unsigned)f2bf(v.y) << 16);
        o.y = (unsigned)f2bf(v.z) | ((unsigned)f2bf(v.w) << 16);
        *(uint2*)&out[i] = o;
    }
}

// Both weight concats in one launch: Wcat[j][k] = (k<128 ? Wl : Wr)
__global__ void sage_wprep2(const float* __restrict__ W1l, const float* __restrict__ W1r,
                            const float* __restrict__ W2l, const float* __restrict__ W2r,
                            unsigned short* __restrict__ wc1, unsigned short* __restrict__ wc2) {
    int idx = blockIdx.x * blockDim.x + threadIdx.x;  // 0..65535
    int which = idx >> 15;
    int id = idx & 32767;
    int j = id >> 8, k = id & 255;
    const float* Wl = which ? W2l : W1l;
    const float* Wr = which ? W2r : W1r;
    unsigned short* o = which ? wc2 : wc1;
    float v = (k < 128) ? Wl[j * 128 + k] : Wr[j * 128 + (k - 128)];
    o[id] = f2bf(v);
}

// ---------------- aggregation (one wave per node, 8 loads in flight) ----------------
// in: [N][128] bf16.  ag: [N][128] bf16 = mean over neighbors (0 if none)

__global__ void __launch_bounds__(256) sage_aggr(const unsigned short* __restrict__ in,
                                                 const int* __restrict__ rowptr,
                                                 const int* __restrict__ srcs,
                                                 unsigned short* __restrict__ ag) {
    int node = blockIdx.x * 4 + (threadIdx.x >> 6);
    if (node >= NNODES) return;
    int lane = threadIdx.x & 63;
    int beg = rowptr[node], end = rowptr[node + 1];
    const unsigned* inu = (const unsigned*)in;   // 64 uints per row
    float s0 = 0.f, s1 = 0.f;
    int i = beg;
    for (; i + 8 <= end; i += 8) {
        unsigned v[8];
        #pragma unroll
        for (int u = 0; u < 8; ++u) v[u] = inu[srcs[i + u] * 64 + lane];
        #pragma unroll
        for (int u = 0; u < 8; ++u) {
            s0 += __uint_as_float(v[u] << 16);
            s1 += __uint_as_float(v[u] & 0xFFFF0000u);
        }
    }
    for (; i < end; ++i) {
        unsigned v = inu[srcs[i] * 64 + lane];
        s0 += __uint_as_float(v << 16);
        s1 += __uint_as_float(v & 0xFFFF0000u);
    }
    int cnt = end - beg;
    float inv = (cnt > 0) ? 1.0f / (float)cnt : 0.0f;
    s0 *= inv; s1 *= inv;
    unsigned* agu = (unsigned*)ag;               // 64 uints per row
    agu[node * 64 + lane] = (unsigned)f2bf(s0) | ((unsigned)f2bf(s1) << 16);
}

// ---------------- GEMM: out[i][j] = sum_k Acat[i][k]*W[j][k] + bias[j] ----------------
// EPI 0: relu + bf16 store (layer 1).
// EPI 1: f32 store with fused row L2-normalize (layer 2) — the 128x128 tile
//        holds complete output rows, so norm = 16-lane shfl reduce + LDS xchg.

template <int EPI>
__global__ void __launch_bounds__(256) sage_gemm(const unsigned short* __restrict__ A0,
                                                 const unsigned short* __restrict__ A1,
                                                 const unsigned short* __restrict__ W,
                                                 const float* __restrict__ bias,
                                                 void* __restrict__ outp) {
    __shared__ unsigned short As[128 * 64];
    __shared__ unsigned short Bs[128 * 64];
    __shared__ float rss[128][2];
    const int tid = threadIdx.x;
    const int bm = blockIdx.x * 128;

    f32x4 acc[4][4];
    const f32x4 zero = {0.f, 0.f, 0.f, 0.f};
    for (int m = 0; m < 4; ++m)
        for (int n = 0; n < 4; ++n) acc[m][n] = zero;

    const int lane = tid & 63, wid = tid >> 6;
    const int wr = wid >> 1, wc = wid & 1;
    const int l16 = lane & 15, lhi = lane >> 4;

    for (int kt = 0; kt < 256; kt += 64) {
        const unsigned short* Asrc = (kt < 128) ? A0 : A1;
        const int kofs = kt & 127;
        __syncthreads();
        #pragma unroll
        for (int it = 0; it < 4; ++it) {
            int idx = it * 2048 + tid * 8;
            int r = idx >> 6, k = idx & 63;
            int row = bm + r; if (row >= NNODES) row = NNODES - 1;
            *(int4*)&As[idx] = *(const int4*)&Asrc[row * 128 + kofs + k];
            *(int4*)&Bs[idx] = *(const int4*)&W[r * 256 + kt + k];
        }
        __syncthreads();
        #pragma unroll
        for (int kk = 0; kk < 64; kk += 32) {
            short8 af[4], bf[4];
            #pragma unroll
            for (int m = 0; m < 4; ++m)
                af[m] = *(const short8*)&As[(wr * 64 + m * 16 + l16) * 64 + kk + lhi * 8];
            #pragma unroll
            for (int n = 0; n < 4; ++n)
                bf[n] = *(const short8*)&Bs[(wc * 64 + n * 16 + l16) * 64 + kk + lhi * 8];
            #pragma unroll
            for (int m = 0; m < 4; ++m)
                #pragma unroll
                for (int n = 0; n < 4; ++n)
                    acc[m][n] = __builtin_amdgcn_mfma_f32_16x16x32_bf16(af[m], bf[n], acc[m][n], 0, 0, 0);
        }
    }

    if (EPI == 0) {
        for (int n = 0; n < 4; ++n) {
            int col = wc * 64 + n * 16 + l16;
            float bv = bias[col];
            for (int m = 0; m < 4; ++m) {
                int row0 = bm + wr * 64 + m * 16 + lhi * 4;
                #pragma unroll
                for (int v = 0; v < 4; ++v) {
                    int row = row0 + v;
                    if (row < NNODES) {
                        float val = fmaxf(acc[m][n][v] + bv, 0.0f);
                        ((unsigned short*)outp)[row * 128 + col] = f2bf(val);
                    }
                }
            }
        }
    } else {
        // bias + row sum-of-squares
        float bv[4];
        #pragma unroll
        for (int n = 0; n < 4; ++n) bv[n] = bias[wc * 64 + n * 16 + l16];
        #pragma unroll
        for (int m = 0; m < 4; ++m) {
            #pragma unroll
            for (int v = 0; v < 4; ++v) {
                float s = 0.f;
                #pragma unroll
                for (int n = 0; n < 4; ++n) {
                    float val = acc[m][n][v] + bv[n];
                    acc[m][n][v] = val;
                    s += val * val;
                }
                s += __shfl_xor(s, 1); s += __shfl_xor(s, 2);
                s += __shfl_xor(s, 4); s += __shfl_xor(s, 8);
                if (l16 == 0) rss[wr * 64 + m * 16 + lhi * 4 + v][wc] = s;
            }
        }
        __syncthreads();
        float* out = (float*)outp;
        #pragma unroll
        for (int m = 0; m < 4; ++m) {
            #pragma unroll
            for (int v = 0; v < 4; ++v) {
                int r = wr * 64 + m * 16 + lhi * 4 + v;
                int row = bm + r;
                float tot = rss[r][0] + rss[r][1];
                float sc = 1.0f / fmaxf(sqrtf(tot), 1e-12f);
                if (row < NNODES) {
                    #pragma unroll
                    for (int n = 0; n < 4; ++n)
                        out[row * 128 + wc * 64 + n * 16 + l16] = acc[m][n][v] * sc;
                }
            }
        }
    }
}

// ---------------- launch ----------------

extern "C" void kernel_launch(void* const* d_in, const int* in_sizes, int n_in,
                              void* d_out, int out_size, void* d_ws, size_t ws_size,
                              hipStream_t stream) {
    const float* x   = (const float*)d_in[0];
    const int* ei    = (const int*)d_in[1];
    const float* W1l = (const float*)d_in[2];
    const float* b1  = (const float*)d_in[3];
    const float* W1r = (const float*)d_in[4];
    const float* W2l = (const float*)d_in[5];
    const float* b2  = (const float*)d_in[6];
    const float* W2r = (const float*)d_in[7];
    const int* srcp = ei;
    const int* dstp = ei + NEDGES;

    char* ws = (char*)d_ws;
    size_t off = 0;
    auto alloc = [&](size_t bytes) -> void* {
        void* p = ws + off;
        off += (bytes + 255) & ~(size_t)255;
        return p;
    };
    int* histmat = (int*)alloc((size_t)NBLK_E * NBUK * 4);   // 613 KB
    int* colofs  = (int*)alloc((size_t)NBLK_E * NBUK * 4);   // 613 KB
    int* totals  = (int*)alloc((size_t)NBUK * 4);
    int* bbase   = (int*)alloc((size_t)(NBUK + 1) * 4);
    int* rowptr  = (int*)alloc((size_t)(NNODES + 1) * 4);
    int* sorted  = (int*)alloc((size_t)NEDGES * 4);
    unsigned* ebuf = (unsigned*)alloc((size_t)NEDGES * 4);
    unsigned short* xb = (unsigned short*)alloc((size_t)NNODES * DDIM * 2);
    unsigned short* ag = (unsigned short*)alloc((size_t)NNODES * DDIM * 2);
    unsigned short* wc1 = (unsigned short*)alloc(128 * 256 * 2);
    unsigned short* wc2 = (unsigned short*)alloc(128 * 256 * 2);
    unsigned short* hb = xb;  // layer-1 output overwrites xb in place

    // CSR build: deterministic counting sort, zero per-edge global atomics
    p1_hist<<<NBLK_E, 256, 0, stream>>>(dstp, histmat);
    p2_colscan<<<(NBUK + 3) / 4, 256, 0, stream>>>(histmat, colofs, totals);
    p2b_bscan<<<1, 1024, 0, stream>>>(totals, bbase, rowptr);
    p3_bucket<<<NBLK_E, 256, 0, stream>>>(srcp, dstp, colofs, bbase, ebuf);
    p4_final<<<NBUK, 256, 0, stream>>>(ebuf, bbase, rowptr, sorted);

    // dtype prep
    sage_cvt<<<(NNODES * DDIM / 4 + 255) / 256, 256, 0, stream>>>(x, xb, NNODES * DDIM);
    sage_wprep2<<<256, 256, 0, stream>>>(W1l, W1r, W2l, W2r, wc1, wc2);

    const int aggr_grid = (NNODES + 3) / 4;
    const int gemm_grid = (NNODES + 127) / 128;

    // layer 1: h = relu(aggr@W1l.T + b1 + x@W1r.T)   (bf16, in place over xb)
    sage_aggr<<<aggr_grid, 256, 0, stream>>>(xb, rowptr, sorted, ag);
    sage_gemm<0><<<gemm_grid, 256, 0, stream>>>(ag, xb, wc1, b1, (void*)hb);
    // layer 2: out = normalize(aggr@W2l.T + b2 + h@W2r.T)  (f32, norm fused)
    sage_aggr<<<aggr_grid, 256, 0, stream>>>(hb, rowptr, sorted, ag);
    sage_gemm<1><<<gemm_grid, 256, 0, stream>>>(ag, hb, wc2, b2, d_out);
}

// Round 9
// 369.778 us; speedup vs baseline: 3.2998x; 1.0528x over previous
//
#include <hip/hip_runtime.h>

#define NNODES 100000
#define NEDGES 1600000
#define DDIM   128
#define NBUK ((NNODES + 127) / 128)        // 782 buckets of 128 nodes
#define EB   8192                          // edges per sort block
#define NBLK_E ((NEDGES + EB - 1) / EB)    // 196

typedef __attribute__((ext_vector_type(8))) short short8;
typedef __attribute__((ext_vector_type(4))) float f32x4;

// f32 -> bf16 round-to-nearest-even (bit trick; NaN irrelevant here)
__device__ __forceinline__ unsigned short f2bf(float f) {
    unsigned u = __float_as_uint(f);
    u += 0x7FFFu + ((u >> 16) & 1u);
    return (unsigned short)(u >> 16);
}

// ---------------- CSR build: deterministic bucketed counting sort ----------------
// No per-edge GLOBAL atomics anywhere (round-5 lesson: 1.6M atomics / 782 addrs
// serialize at ~210ns per same-line RMW = 431us). All per-edge atomics are LDS.

// P1: per-block LDS histogram over buckets -> histmat[blk][NBUK] (coalesced)
__global__ void __launch_bounds__(256) p1_hist(const int* __restrict__ dst,
                                               int* __restrict__ histmat) {
    __shared__ int h[NBUK];
    for (int i = threadIdx.x; i < NBUK; i += 256) h[i] = 0;
    __syncthreads();
    int base = blockIdx.x * EB;
    int end = base + EB; if (end > NEDGES) end = NEDGES;
    for (int i = base + threadIdx.x; i < end; i += 256)
        atomicAdd(&h[dst[i] >> 7], 1);
    __syncthreads();
    for (int i = threadIdx.x; i < NBUK; i += 256)
        histmat[blockIdx.x * NBUK + i] = h[i];
}

// P2a: per-bucket exclusive scan down the block axis -> colofs + totals
__global__ void __launch_bounds__(256) p2_colscan(const int* __restrict__ histmat,
                                                  int* __restrict__ colofs,
                                                  int* __restrict__ totals) {
    int b = blockIdx.x * 4 + (threadIdx.x >> 6);
    if (b >= NBUK) return;
    int lane = threadIdx.x & 63;
    int running = 0;
    #pragma unroll
    for (int r = 0; r < (NBLK_E + 63) / 64; ++r) {
        int blk = r * 64 + lane;
        int v = (blk < NBLK_E) ? histmat[blk * NBUK + b] : 0;
        int sc = v;
        for (int o = 1; o < 64; o <<= 1) {
            int u = __shfl_up(sc, o);
            if (lane >= o) sc += u;
        }
        if (blk < NBLK_E) colofs[blk * NBUK + b] = running + sc - v;
        running += __shfl(sc, 63);
    }
    if (lane == 0) totals[b] = running;
}

// P2b: scan bucket totals -> bbase[0..NBUK]; also rowptr[NNODES]
__global__ void __launch_bounds__(1024) p2b_bscan(const int* __restrict__ totals,
                                                  int* __restrict__ bbase,
                                                  int* __restrict__ rowptr) {
    __shared__ int sm[1024];
    int t = threadIdx.x;
    int v = (t < NBUK) ? totals[t] : 0;
    sm[t] = v;
    __syncthreads();
    for (int o = 1; o < 1024; o <<= 1) {
        int u = (t >= o) ? sm[t - o] : 0;
        __syncthreads();
        sm[t] += u;
        __syncthreads();
    }
    if (t < NBUK) bbase[t] = sm[t] - v;
    if (t == 0) { bbase[NBUK] = NEDGES; rowptr[NNODES] = NEDGES; }
}

// P3: deterministic bucket-grouped scatter via LDS cursors (init bbase+colofs)
__global__ void __launch_bounds__(256) p3_bucket(const int* __restrict__ src,
                                                 const int* __restrict__ dst,
                                                 const int* __restrict__ colofs,
                                                 const int* __restrict__ bbase,
                                                 unsigned* __restrict__ ebuf) {
    __shared__ int cur[NBUK];
    for (int i = threadIdx.x; i < NBUK; i += 256)
        cur[i] = bbase[i] + colofs[blockIdx.x * NBUK + i];
    __syncthreads();
    int base = blockIdx.x * EB;
    int end = base + EB; if (end > NEDGES) end = NEDGES;
    for (int i = base + threadIdx.x; i < end; i += 256) {
        int d = dst[i];
        int pos = atomicAdd(&cur[d >> 7], 1);
        ebuf[pos] = ((unsigned)(d & 127) << 17) | (unsigned)src[i];
    }
}

// P4: one block per bucket: per-node LDS count+scan -> rowptr (coalesced) and
// sorted[] (writes confined to the bucket's ~8KB window -> full-line writebacks)
__global__ void __launch_bounds__(256) p4_final(const unsigned* __restrict__ ebuf,
                                                const int* __restrict__ bbase,
                                                int* __restrict__ rowptr,
                                                int* __restrict__ sorted) {
    __shared__ int cnt[128];
    __shared__ int ofs[128];
    int b = blockIdx.x;
    int s = bbase[b], e = bbase[b + 1];
    int t = threadIdx.x;
    if (t < 128) cnt[t] = 0;
    __syncthreads();
    for (int i = s + t; i < e; i += 256)
        atomicAdd(&cnt[ebuf[i] >> 17], 1);
    __syncthreads();
    if (t < 128) ofs[t] = cnt[t];
    __syncthreads();
    for (int o = 1; o < 128; o <<= 1) {
        int u = (t >= o && t < 128) ? ofs[t - o] : 0;
        __syncthreads();
        if (t < 128) ofs[t] += u;
        __syncthreads();
    }
    int nodebase = b << 7;
    if (t < 128) {
        int excl = ofs[t] - cnt[t];
        if (nodebase + t < NNODES) rowptr[nodebase + t] = s + excl;
        cnt[t] = excl;  // reuse as cursor
    }
    __syncthreads();
    for (int i = s + t; i < e; i += 256) {
        unsigned v = ebuf[i];
        int r = atomicAdd(&cnt[v >> 17], 1);
        sorted[s + r] = (int)(v & 0x1FFFFu);
    }
}

// ---------------- dtype prep ----------------

__global__ void sage_cvt(const float* __restrict__ in, unsigned short* __restrict__ out, int n) {
    int i = (blockIdx.x * blockDim.x + threadIdx.x) * 4;
    if (i < n) {
        float4 v = *(const float4*)&in[i];
        uint2 o;
        o.x = (unsigned)f2bf(v.x) | ((unsigned)f2bf(v.y) << 16);
        o.y = (unsigned)f2bf(v.z) | ((unsigned)f2bf(v.w) << 16);
        *(uint2*)&out[i] = o;
    }
}

// Both weight concats in one launch: Wcat[j][k] = (k<128 ? Wl : Wr)
__global__ void sage_wprep2(const float* __restrict__ W1l, const float* __restrict__ W1r,
                            const float* __restrict__ W2l, const float* __restrict__ W2r,
                            unsigned short* __restrict__ wc1, unsigned short* __restrict__ wc2) {
    int idx = blockIdx.x * blockDim.x + threadIdx.x;  // 0..65535
    int which = idx >> 15;
    int id = idx & 32767;
    int j = id >> 8, k = id & 255;
    const float* Wl = which ? W2l : W1l;
    const float* Wr = which ? W2r : W1r;
    unsigned short* o = which ? wc2 : wc1;
    float v = (k < 128) ? Wl[j * 128 + k] : Wr[j * 128 + (k - 128)];
    o[id] = f2bf(v);
}

// ---------------- aggregation (one wave per node, dwordx4 gather) ----------------
// 4 edges per wave-load: lane = g*16+s reads 16B (8 feats) of row srcs[i+g].
// Same cache lines as the dword version but 4x fewer gather instructions,
// 4x fewer index loads, 4x bytes per outstanding-load slot.

__global__ void __launch_bounds__(256) sage_aggr(const unsigned short* __restrict__ in,
                                                 const int* __restrict__ rowptr,
                                                 const int* __restrict__ srcs,
                                                 unsigned short* __restrict__ ag) {
    int node = blockIdx.x * 4 + (threadIdx.x >> 6);
    if (node >= NNODES) return;
    int lane = threadIdx.x & 63;
    int g = lane >> 4, s = lane & 15;
    int beg = rowptr[node], end = rowptr[node + 1];
    const uint4* inq = (const uint4*)in;   // 16 uint4 per row
    float f[8];
    #pragma unroll
    for (int j = 0; j < 8; ++j) f[j] = 0.f;

    int i = beg;
    for (; i + 8 <= end; i += 8) {
        uint4 va = inq[srcs[i + g] * 16 + s];
        uint4 vb = inq[srcs[i + 4 + g] * 16 + s];
        f[0] += __uint_as_float(va.x << 16);
        f[1] += __uint_as_float(va.x & 0xFFFF0000u);
        f[2] += __uint_as_float(va.y << 16);
        f[3] += __uint_as_float(va.y & 0xFFFF0000u);
        f[4] += __uint_as_float(va.z << 16);
        f[5] += __uint_as_float(va.z & 0xFFFF0000u);
        f[6] += __uint_as_float(va.w << 16);
        f[7] += __uint_as_float(va.w & 0xFFFF0000u);
        f[0] += __uint_as_float(vb.x << 16);
        f[1] += __uint_as_float(vb.x & 0xFFFF0000u);
        f[2] += __uint_as_float(vb.y << 16);
        f[3] += __uint_as_float(vb.y & 0xFFFF0000u);
        f[4] += __uint_as_float(vb.z << 16);
        f[5] += __uint_as_float(vb.z & 0xFFFF0000u);
        f[6] += __uint_as_float(vb.w << 16);
        f[7] += __uint_as_float(vb.w & 0xFFFF0000u);
    }
    for (; i < end; i += 4) {
        if (i + g < end) {
            uint4 v = inq[srcs[i + g] * 16 + s];
            f[0] += __uint_as_float(v.x << 16);
            f[1] += __uint_as_float(v.x & 0xFFFF0000u);
            f[2] += __uint_as_float(v.y << 16);
            f[3] += __uint_as_float(v.y & 0xFFFF0000u);
            f[4] += __uint_as_float(v.z << 16);
            f[5] += __uint_as_float(v.z & 0xFFFF0000u);
            f[6] += __uint_as_float(v.w << 16);
            f[7] += __uint_as_float(v.w & 0xFFFF0000u);
        }
    }
    // combine the 4 subgroup partials (lane xor 16, 32)
    #pragma unroll
    for (int j = 0; j < 8; ++j) {
        f[j] += __shfl_xor(f[j], 16);
        f[j] += __shfl_xor(f[j], 32);
    }
    int cnt = end - beg;
    float inv = (cnt > 0) ? 1.0f / (float)cnt : 0.0f;
    if (g == 0) {
        uint4 o;
        o.x = (unsigned)f2bf(f[0] * inv) | ((unsigned)f2bf(f[1] * inv) << 16);
        o.y = (unsigned)f2bf(f[2] * inv) | ((unsigned)f2bf(f[3] * inv) << 16);
        o.z = (unsigned)f2bf(f[4] * inv) | ((unsigned)f2bf(f[5] * inv) << 16);
        o.w = (unsigned)f2bf(f[6] * inv) | ((unsigned)f2bf(f[7] * inv) << 16);
        ((uint4*)ag)[node * 16 + s] = o;
    }
}

// ---------------- GEMM: out[i][j] = sum_k Acat[i][k]*W[j][k] + bias[j] ----------------
// EPI 0: relu + bf16 store (layer 1).
// EPI 1: f32 store with fused row L2-normalize (layer 2) — the 128x128 tile
//        holds complete output rows, so norm = 16-lane shfl reduce + LDS xchg.

template <int EPI>
__global__ void __launch_bounds__(256) sage_gemm(const unsigned short* __restrict__ A0,
                                                 const unsigned short* __restrict__ A1,
                                                 const unsigned short* __restrict__ W,
                                                 const float* __restrict__ bias,
                                                 void* __restrict__ outp) {
    __shared__ unsigned short As[128 * 64];
    __shared__ unsigned short Bs[128 * 64];
    __shared__ float rss[128][2];
    const int tid = threadIdx.x;
    const int bm = blockIdx.x * 128;

    f32x4 acc[4][4];
    const f32x4 zero = {0.f, 0.f, 0.f, 0.f};
    for (int m = 0; m < 4; ++m)
        for (int n = 0; n < 4; ++n) acc[m][n] = zero;

    const int lane = tid & 63, wid = tid >> 6;
    const int wr = wid >> 1, wc = wid & 1;
    const int l16 = lane & 15, lhi = lane >> 4;

    for (int kt = 0; kt < 256; kt += 64) {
        const unsigned short* Asrc = (kt < 128) ? A0 : A1;
        const int kofs = kt & 127;
        __syncthreads();
        #pragma unroll
        for (int it = 0; it < 4; ++it) {
            int idx = it * 2048 + tid * 8;
            int r = idx >> 6, k = idx & 63;
            int row = bm + r; if (row >= NNODES) row = NNODES - 1;
            *(int4*)&As[idx] = *(const int4*)&Asrc[row * 128 + kofs + k];
            *(int4*)&Bs[idx] = *(const int4*)&W[r * 256 + kt + k];
        }
        __syncthreads();
        #pragma unroll
        for (int kk = 0; kk < 64; kk += 32) {
            short8 af[4], bf[4];
            #pragma unroll
            for (int m = 0; m < 4; ++m)
                af[m] = *(const short8*)&As[(wr * 64 + m * 16 + l16) * 64 + kk + lhi * 8];
            #pragma unroll
            for (int n = 0; n < 4; ++n)
                bf[n] = *(const short8*)&Bs[(wc * 64 + n * 16 + l16) * 64 + kk + lhi * 8];
            #pragma unroll
            for (int m = 0; m < 4; ++m)
                #pragma unroll
                for (int n = 0; n < 4; ++n)
                    acc[m][n] = __builtin_amdgcn_mfma_f32_16x16x32_bf16(af[m], bf[n], acc[m][n], 0, 0, 0);
        }
    }

    if (EPI == 0) {
        for (int n = 0; n < 4; ++n) {
            int col = wc * 64 + n * 16 + l16;
            float bv = bias[col];
            for (int m = 0; m < 4; ++m) {
                int row0 = bm + wr * 64 + m * 16 + lhi * 4;
                #pragma unroll
                for (int v = 0; v < 4; ++v) {
                    int row = row0 + v;
                    if (row < NNODES) {
                        float val = fmaxf(acc[m][n][v] + bv, 0.0f);
                        ((unsigned short*)outp)[row * 128 + col] = f2bf(val);
                    }
                }
            }
        }
    } else {
        // bias + row sum-of-squares
        float bv[4];
        #pragma unroll
        for (int n = 0; n < 4; ++n) bv[n] = bias[wc * 64 + n * 16 + l16];
        #pragma unroll
        for (int m = 0; m < 4; ++m) {
            #pragma unroll
            for (int v = 0; v < 4; ++v) {
                float s = 0.f;
                #pragma unroll
                for (int n = 0; n < 4; ++n) {
                    float val = acc[m][n][v] + bv[n];
                    acc[m][n][v] = val;
                    s += val * val;
                }
                s += __shfl_xor(s, 1); s += __shfl_xor(s, 2);
                s += __shfl_xor(s, 4); s += __shfl_xor(s, 8);
                if (l16 == 0) rss[wr * 64 + m * 16 + lhi * 4 + v][wc] = s;
            }
        }
        __syncthreads();
        float* out = (float*)outp;
        #pragma unroll
        for (int m = 0; m < 4; ++m) {
            #pragma unroll
            for (int v = 0; v < 4; ++v) {
                int r = wr * 64 + m * 16 + lhi * 4 + v;
                int row = bm + r;
                float tot = rss[r][0] + rss[r][1];
                float sc = 1.0f / fmaxf(sqrtf(tot), 1e-12f);
                if (row < NNODES) {
                    #pragma unroll
                    for (int n = 0; n < 4; ++n)
                        out[row * 128 + wc * 64 + n * 16 + l16] = acc[m][n][v] * sc;
                }
            }
        }
    }
}

// ---------------- launch ----------------

extern "C" void kernel_launch(void* const* d_in, const int* in_sizes, int n_in,
                              void* d_out, int out_size, void* d_ws, size_t ws_size,
                              hipStream_t stream) {
    const float* x   = (const float*)d_in[0];
    const int* ei    = (const int*)d_in[1];
    const float* W1l = (const float*)d_in[2];
    const float* b1  = (const float*)d_in[3];
    const float* W1r = (const float*)d_in[4];
    const float* W2l = (const float*)d_in[5];
    const float* b2  = (const float*)d_in[6];
    const float* W2r = (const float*)d_in[7];
    const int* srcp = ei;
    const int* dstp = ei + NEDGES;

    char* ws = (char*)d_ws;
    size_t off = 0;
    auto alloc = [&](size_t bytes) -> void* {
        void* p = ws + off;
        off += (bytes + 255) & ~(size_t)255;
        return p;
    };
    int* histmat = (int*)alloc((size_t)NBLK_E * NBUK * 4);   // 613 KB
    int* colofs  = (int*)alloc((size_t)NBLK_E * NBUK * 4);   // 613 KB
    int* totals  = (int*)alloc((size_t)NBUK * 4);
    int* bbase   = (int*)alloc((size_t)(NBUK + 1) * 4);
    int* rowptr  = (int*)alloc((size_t)(NNODES + 1) * 4);
    int* sorted  = (int*)alloc((size_t)NEDGES * 4);
    unsigned* ebuf = (unsigned*)alloc((size_t)NEDGES * 4);
    unsigned short* xb = (unsigned short*)alloc((size_t)NNODES * DDIM * 2);
    unsigned short* ag = (unsigned short*)alloc((size_t)NNODES * DDIM * 2);
    unsigned short* wc1 = (unsigned short*)alloc(128 * 256 * 2);
    unsigned short* wc2 = (unsigned short*)alloc(128 * 256 * 2);
    unsigned short* hb = xb;  // layer-1 output overwrites xb in place

    // CSR build: deterministic counting sort, zero per-edge global atomics
    p1_hist<<<NBLK_E, 256, 0, stream>>>(dstp, histmat);
    p2_colscan<<<(NBUK + 3) / 4, 256, 0, stream>>>(histmat, colofs, totals);
    p2b_bscan<<<1, 1024, 0, stream>>>(totals, bbase, rowptr);
    p3_bucket<<<NBLK_E, 256, 0, stream>>>(srcp, dstp, colofs, bbase, ebuf);
    p4_final<<<NBUK, 256, 0, stream>>>(ebuf, bbase, rowptr, sorted);

    // dtype prep
    sage_cvt<<<(NNODES * DDIM / 4 + 255) / 256, 256, 0, stream>>>(x, xb, NNODES * DDIM);
    sage_wprep2<<<256, 256, 0, stream>>>(W1l, W1r, W2l, W2r, wc1, wc2);

    const int aggr_grid = (NNODES + 3) / 4;
    const int gemm_grid = (NNODES + 127) / 128;

    // layer 1: h = relu(aggr@W1l.T + b1 + x@W1r.T)   (bf16, in place over xb)
    sage_aggr<<<aggr_grid, 256, 0, stream>>>(xb, rowptr, sorted, ag);
    sage_gemm<0><<<gemm_grid, 256, 0, stream>>>(ag, xb, wc1, b1, (void*)hb);
    // layer 2: out = normalize(aggr@W2l.T + b2 + h@W2r.T)  (f32, norm fused)
    sage_aggr<<<aggr_grid, 256, 0, stream>>>(hb, rowptr, sorted, ag);
    sage_gemm<1><<<gemm_grid, 256, 0, stream>>>(ag, hb, wc2, b2, d_out);
}

// Round 11
// 364.636 us; speedup vs baseline: 3.3463x; 1.0141x over previous
//
#include <hip/hip_runtime.h>

#define NNODES 100000
#define NEDGES 1600000
#define DDIM   128
#define NBUK ((NNODES + 127) / 128)        // 782 buckets of 128 nodes
#define EB   8192                          // edges per sort block
#define NBLK_E ((NEDGES + EB - 1) / EB)    // 196

typedef __attribute__((ext_vector_type(8))) short short8;
typedef __attribute__((ext_vector_type(4))) float f32x4;
typedef __attribute__((ext_vector_type(2))) float f32x2;

// f32 -> bf16 round-to-nearest-even (bit trick; NaN irrelevant here)
__device__ __forceinline__ unsigned short f2bf(float f) {
    unsigned u = __float_as_uint(f);
    u += 0x7FFFu + ((u >> 16) & 1u);
    return (unsigned short)(u >> 16);
}

// ---------------- CSR build: deterministic bucketed counting sort ----------------
// No per-edge GLOBAL atomics anywhere (round-5 lesson: 1.6M atomics / 782 addrs
// serialize at ~210ns per same-line RMW = 431us). All per-edge atomics are LDS.

// P1: per-block LDS histogram over buckets -> histmat[blk][NBUK] (coalesced)
__global__ void __launch_bounds__(256) p1_hist(const int* __restrict__ dst,
                                               int* __restrict__ histmat) {
    __shared__ int h[NBUK];
    for (int i = threadIdx.x; i < NBUK; i += 256) h[i] = 0;
    __syncthreads();
    int base = blockIdx.x * EB;
    int end = base + EB; if (end > NEDGES) end = NEDGES;
    for (int i = base + threadIdx.x; i < end; i += 256)
        atomicAdd(&h[dst[i] >> 7], 1);
    __syncthreads();
    for (int i = threadIdx.x; i < NBUK; i += 256)
        histmat[blockIdx.x * NBUK + i] = h[i];
}

// P2a: per-bucket exclusive scan down the block axis -> colofs + totals
__global__ void __launch_bounds__(256) p2_colscan(const int* __restrict__ histmat,
                                                  int* __restrict__ colofs,
                                                  int* __restrict__ totals) {
    int b = blockIdx.x * 4 + (threadIdx.x >> 6);
    if (b >= NBUK) return;
    int lane = threadIdx.x & 63;
    int running = 0;
    #pragma unroll
    for (int r = 0; r < (NBLK_E + 63) / 64; ++r) {
        int blk = r * 64 + lane;
        int v = (blk < NBLK_E) ? histmat[blk * NBUK + b] : 0;
        int sc = v;
        for (int o = 1; o < 64; o <<= 1) {
            int u = __shfl_up(sc, o);
            if (lane >= o) sc += u;
        }
        if (blk < NBLK_E) colofs[blk * NBUK + b] = running + sc - v;
        running += __shfl(sc, 63);
    }
    if (lane == 0) totals[b] = running;
}

// P2b: scan bucket totals -> bbase[0..NBUK]; also rowptr[NNODES]
__global__ void __launch_bounds__(1024) p2b_bscan(const int* __restrict__ totals,
                                                  int* __restrict__ bbase,
                                                  int* __restrict__ rowptr) {
    __shared__ int sm[1024];
    int t = threadIdx.x;
    int v = (t < NBUK) ? totals[t] : 0;
    sm[t] = v;
    __syncthreads();
    for (int o = 1; o < 1024; o <<= 1) {
        int u = (t >= o) ? sm[t - o] : 0;
        __syncthreads();
        sm[t] += u;
        __syncthreads();
    }
    if (t < NBUK) bbase[t] = sm[t] - v;
    if (t == 0) { bbase[NBUK] = NEDGES; rowptr[NNODES] = NEDGES; }
}

// P3: deterministic bucket-grouped scatter via LDS cursors (init bbase+colofs)
__global__ void __launch_bounds__(256) p3_bucket(const int* __restrict__ src,
                                                 const int* __restrict__ dst,
                                                 const int* __restrict__ colofs,
                                                 const int* __restrict__ bbase,
                                                 unsigned* __restrict__ ebuf) {
    __shared__ int cur[NBUK];
    for (int i = threadIdx.x; i < NBUK; i += 256)
        cur[i] = bbase[i] + colofs[blockIdx.x * NBUK + i];
    __syncthreads();
    int base = blockIdx.x * EB;
    int end = base + EB; if (end > NEDGES) end = NEDGES;
    for (int i = base + threadIdx.x; i < end; i += 256) {
        int d = dst[i];
        int pos = atomicAdd(&cur[d >> 7], 1);
        ebuf[pos] = ((unsigned)(d & 127) << 17) | (unsigned)src[i];
    }
}

// P4: one block per bucket: per-node LDS count+scan -> rowptr (coalesced) and
// sorted[] (writes confined to the bucket's ~8KB window -> full-line writebacks)
__global__ void __launch_bounds__(256) p4_final(const unsigned* __restrict__ ebuf,
                                                const int* __restrict__ bbase,
                                                int* __restrict__ rowptr,
                                                int* __restrict__ sorted) {
    __shared__ int cnt[128];
    __shared__ int ofs[128];
    int b = blockIdx.x;
    int s = bbase[b], e = bbase[b + 1];
    int t = threadIdx.x;
    if (t < 128) cnt[t] = 0;
    __syncthreads();
    for (int i = s + t; i < e; i += 256)
        atomicAdd(&cnt[ebuf[i] >> 17], 1);
    __syncthreads();
    if (t < 128) ofs[t] = cnt[t];
    __syncthreads();
    for (int o = 1; o < 128; o <<= 1) {
        int u = (t >= o && t < 128) ? ofs[t - o] : 0;
        __syncthreads();
        if (t < 128) ofs[t] += u;
        __syncthreads();
    }
    int nodebase = b << 7;
    if (t < 128) {
        int excl = ofs[t] - cnt[t];
        if (nodebase + t < NNODES) rowptr[nodebase + t] = s + excl;
        cnt[t] = excl;  // reuse as cursor
    }
    __syncthreads();
    for (int i = s + t; i < e; i += 256) {
        unsigned v = ebuf[i];
        int r = atomicAdd(&cnt[v >> 17], 1);
        sorted[s + r] = (int)(v & 0x1FFFFu);
    }
}

// ---------------- dtype prep ----------------

__global__ void sage_cvt(const float* __restrict__ in, unsigned short* __restrict__ out, int n) {
    int i = (blockIdx.x * blockDim.x + threadIdx.x) * 4;
    if (i < n) {
        float4 v = *(const float4*)&in[i];
        uint2 o;
        o.x = (unsigned)f2bf(v.x) | ((unsigned)f2bf(v.y) << 16);
        o.y = (unsigned)f2bf(v.z) | ((unsigned)f2bf(v.w) << 16);
        *(uint2*)&out[i] = o;
    }
}

// Both weight concats in one launch: Wcat[j][k] = (k<128 ? Wl : Wr)
__global__ void sage_wprep2(const float* __restrict__ W1l, const float* __restrict__ W1r,
                            const float* __restrict__ W2l, const float* __restrict__ W2r,
                            unsigned short* __restrict__ wc1, unsigned short* __restrict__ wc2) {
    int idx = blockIdx.x * blockDim.x + threadIdx.x;  // 0..65535
    int which = idx >> 15;
    int id = idx & 32767;
    int j = id >> 8, k = id & 255;
    const float* Wl = which ? W2l : W1l;
    const float* Wr = which ? W2r : W1r;
    unsigned short* o = which ? wc2 : wc1;
    float v = (k < 128) ? Wl[j * 128 + k] : Wr[j * 128 + (k - 128)];
    o[id] = f2bf(v);
}

// ---------------- aggregation (one wave per node, dwordx4 gather) ----------------
// 4 edges per wave-load: lane = g*16+s reads 16B (8 feats) of row srcs[i+g].
// 16-edge main loop (4 loads in flight); f32x2 accumulators -> v_pk_add_f32.

__global__ void __launch_bounds__(256) sage_aggr(const unsigned short* __restrict__ in,
                                                 const int* __restrict__ rowptr,
                                                 const int* __restrict__ srcs,
                                                 unsigned short* __restrict__ ag) {
    int node = blockIdx.x * 4 + (threadIdx.x >> 6);
    if (node >= NNODES) return;
    int lane = threadIdx.x & 63;
    int g = lane >> 4, s = lane & 15;
    int beg = rowptr[node], end = rowptr[node + 1];
    const uint4* inq = (const uint4*)in;   // 16 uint4 per row
    f32x2 f0 = {0.f, 0.f}, f1 = {0.f, 0.f}, f2 = {0.f, 0.f}, f3 = {0.f, 0.f};

    auto accum = [&](uint4 v) {
        f0 += (f32x2){__uint_as_float(v.x << 16), __uint_as_float(v.x & 0xFFFF0000u)};
        f1 += (f32x2){__uint_as_float(v.y << 16), __uint_as_float(v.y & 0xFFFF0000u)};
        f2 += (f32x2){__uint_as_float(v.z << 16), __uint_as_float(v.z & 0xFFFF0000u)};
        f3 += (f32x2){__uint_as_float(v.w << 16), __uint_as_float(v.w & 0xFFFF0000u)};
    };

    int i = beg;
    for (; i + 16 <= end; i += 16) {
        uint4 va = inq[srcs[i + g] * 16 + s];
        uint4 vb = inq[srcs[i + 4 + g] * 16 + s];
        uint4 vc = inq[srcs[i + 8 + g] * 16 + s];
        uint4 vd = inq[srcs[i + 12 + g] * 16 + s];
        accum(va); accum(vb); accum(vc); accum(vd);
    }
    for (; i + 4 <= end; i += 4)
        accum(inq[srcs[i + g] * 16 + s]);
    if (i + g < end)
        accum(inq[srcs[i + g] * 16 + s]);

    // combine the 4 subgroup partials (lane xor 16, 32)
    f0.x += __shfl_xor(f0.x, 16); f0.y += __shfl_xor(f0.y, 16);
    f1.x += __shfl_xor(f1.x, 16); f1.y += __shfl_xor(f1.y, 16);
    f2.x += __shfl_xor(f2.x, 16); f2.y += __shfl_xor(f2.y, 16);
    f3.x += __shfl_xor(f3.x, 16); f3.y += __shfl_xor(f3.y, 16);
    f0.x += __shfl_xor(f0.x, 32); f0.y += __shfl_xor(f0.y, 32);
    f1.x += __shfl_xor(f1.x, 32); f1.y += __shfl_xor(f1.y, 32);
    f2.x += __shfl_xor(f2.x, 32); f2.y += __shfl_xor(f2.y, 32);
    f3.x += __shfl_xor(f3.x, 32); f3.y += __shfl_xor(f3.y, 32);

    int cnt = end - beg;
    float inv = (cnt > 0) ? 1.0f / (float)cnt : 0.0f;
    if (g == 0) {
        uint4 o;
        o.x = (unsigned)f2bf(f0.x * inv) | ((unsigned)f2bf(f0.y * inv) << 16);
        o.y = (unsigned)f2bf(f1.x * inv) | ((unsigned)f2bf(f1.y * inv) << 16);
        o.z = (unsigned)f2bf(f2.x * inv) | ((unsigned)f2bf(f2.y * inv) << 16);
        o.w = (unsigned)f2bf(f3.x * inv) | ((unsigned)f2bf(f3.y * inv) << 16);
        ((uint4*)ag)[node * 16 + s] = o;
    }
}

// ---------------- GEMM: out[i][j] = sum_k Acat[i][k]*W[j][k] + bias[j] ----------------
// EPI 0: relu + bf16 store (layer 1).
// EPI 1: f32 store with fused row L2-normalize (layer 2).

template <int EPI>
__global__ void __launch_bounds__(256) sage_gemm(const unsigned short* __restrict__ A0,
                                                 const unsigned short* __restrict__ A1,
                                                 const unsigned short* __restrict__ W,
                                                 const float* __restrict__ bias,
                                                 void* __restrict__ outp) {
    __shared__ unsigned short As[128 * 64];
    __shared__ unsigned short Bs[128 * 64];
    __shared__ float rss[128][2];
    const int tid = threadIdx.x;
    const int bm = blockIdx.x * 128;

    f32x4 acc[4][4];
    const f32x4 zero = {0.f, 0.f, 0.f, 0.f};
    for (int m = 0; m < 4; ++m)
        for (int n = 0; n < 4; ++n) acc[m][n] = zero;

    const int lane = tid & 63, wid = tid >> 6;
    const int wr = wid >> 1, wc = wid & 1;
    const int l16 = lane & 15, lhi = lane >> 4;

    for (int kt = 0; kt < 256; kt += 64) {
        const unsigned short* Asrc = (kt < 128) ? A0 : A1;
        const int kofs = kt & 127;
        __syncthreads();
        #pragma unroll
        for (int it = 0; it < 4; ++it) {
            int idx = it * 2048 + tid * 8;
            int r = idx >> 6, k = idx & 63;
            int row = bm + r; if (row >= NNODES) row = NNODES - 1;
            *(int4*)&As[idx] = *(const int4*)&Asrc[row * 128 + kofs + k];
            *(int4*)&Bs[idx] = *(const int4*)&W[r * 256 + kt + k];
        }
        __syncthreads();
        #pragma unroll
        for (int kk = 0; kk < 64; kk += 32) {
            short8 af[4], bf[4];
            #pragma unroll
            for (int m = 0; m < 4; ++m)
                af[m] = *(const short8*)&As[(wr * 64 + m * 16 + l16) * 64 + kk + lhi * 8];
            #pragma unroll
            for (int n = 0; n < 4; ++n)
                bf[n] = *(const short8*)&Bs[(wc * 64 + n * 16 + l16) * 64 + kk + lhi * 8];
            #pragma unroll
            for (int m = 0; m < 4; ++m)
                #pragma unroll
                for (int n = 0; n < 4; ++n)
                    acc[m][n] = __builtin_amdgcn_mfma_f32_16x16x32_bf16(af[m], bf[n], acc[m][n], 0, 0, 0);
        }
    }

    if (EPI == 0) {
        for (int n = 0; n < 4; ++n) {
            int col = wc * 64 + n * 16 + l16;
            float bv = bias[col];
            for (int m = 0; m < 4; ++m) {
                int row0 = bm + wr * 64 + m * 16 + lhi * 4;
                #pragma unroll
                for (int v = 0; v < 4; ++v) {
                    int row = row0 + v;
                    if (row < NNODES) {
                        float val = fmaxf(acc[m][n][v] + bv, 0.0f);
                        ((unsigned short*)outp)[row * 128 + col] = f2bf(val);
                    }
                }
            }
        }
    } else {
        float bv[4];
        #pragma unroll
        for (int n = 0; n < 4; ++n) bv[n] = bias[wc * 64 + n * 16 + l16];
        #pragma unroll
        for (int m = 0; m < 4; ++m) {
            #pragma unroll
            for (int v = 0; v < 4; ++v) {
                float s = 0.f;
                #pragma unroll
                for (int n = 0; n < 4; ++n) {
                    float val = acc[m][n][v] + bv[n];
                    acc[m][n][v] = val;
                    s += val * val;
                }
                s += __shfl_xor(s, 1); s += __shfl_xor(s, 2);
                s += __shfl_xor(s, 4); s += __shfl_xor(s, 8);
                if (l16 == 0) rss[wr * 64 + m * 16 + lhi * 4 + v][wc] = s;
            }
        }
        __syncthreads();
        float* out = (float*)outp;
        #pragma unroll
        for (int m = 0; m < 4; ++m) {
            #pragma unroll
            for (int v = 0; v < 4; ++v) {
                int r = wr * 64 + m * 16 + lhi * 4 + v;
                int row = bm + r;
                float tot = rss[r][0] + rss[r][1];
                float sc = 1.0f / fmaxf(sqrtf(tot), 1e-12f);
                if (row < NNODES) {
                    #pragma unroll
                    for (int n = 0; n < 4; ++n)
                        out[row * 128 + wc * 64 + n * 16 + l16] = acc[m][n][v] * sc;
                }
            }
        }
    }
}

// ---------------- launch ----------------

extern "C" void kernel_launch(void* const* d_in, const int* in_sizes, int n_in,
                              void* d_out, int out_size, void* d_ws, size_t ws_size,
                              hipStream_t stream) {
    const float* x   = (const float*)d_in[0];
    const int* ei    = (const int*)d_in[1];
    const float* W1l = (const float*)d_in[2];
    const float* b1  = (const float*)d_in[3];
    const float* W1r = (const float*)d_in[4];
    const float* W2l = (const float*)d_in[5];
    const float* b2  = (const float*)d_in[6];
    const float* W2r = (const float*)d_in[7];
    const int* srcp = ei;
    const int* dstp = ei + NEDGES;

    char* ws = (char*)d_ws;
    size_t off = 0;
    auto alloc = [&](size_t bytes) -> void* {
        void* p = ws + off;
        off += (bytes + 255) & ~(size_t)255;
        return p;
    };
    int* histmat = (int*)alloc((size_t)NBLK_E * NBUK * 4);   // 613 KB
    int* colofs  = (int*)alloc((size_t)NBLK_E * NBUK * 4);   // 613 KB
    int* totals  = (int*)alloc((size_t)NBUK * 4);
    int* bbase   = (int*)alloc((size_t)(NBUK + 1) * 4);
    int* rowptr  = (int*)alloc((size_t)(NNODES + 1) * 4);
    int* sorted  = (int*)alloc((size_t)NEDGES * 4);
    unsigned* ebuf = (unsigned*)alloc((size_t)NEDGES * 4);
    unsigned short* xb = (unsigned short*)alloc((size_t)NNODES * DDIM * 2);
    unsigned short* ag = (unsigned short*)alloc((size_t)NNODES * DDIM * 2);
    unsigned short* wc1 = (unsigned short*)alloc(128 * 256 * 2);
    unsigned short* wc2 = (unsigned short*)alloc(128 * 256 * 2);
    unsigned short* hb = xb;  // layer-1 output overwrites xb in place

    // CSR build: deterministic counting sort, zero per-edge global atomics
    p1_hist<<<NBLK_E, 256, 0, stream>>>(dstp, histmat);
    p2_colscan<<<(NBUK + 3) / 4, 256, 0, stream>>>(histmat, colofs, totals);
    p2b_bscan<<<1, 1024, 0, stream>>>(totals, bbase, rowptr);
    p3_bucket<<<NBLK_E, 256, 0, stream>>>(srcp, dstp, colofs, bbase, ebuf);
    p4_final<<<NBUK, 256, 0, stream>>>(ebuf, bbase, rowptr, sorted);

    // dtype prep
    sage_cvt<<<(NNODES * DDIM / 4 + 255) / 256, 256, 0, stream>>>(x, xb, NNODES * DDIM);
    sage_wprep2<<<256, 256, 0, stream>>>(W1l, W1r, W2l, W2r, wc1, wc2);

    const int aggr_grid = (NNODES + 3) / 4;
    const int gemm_grid = (NNODES + 127) / 128;

    // layer 1: h = relu(aggr@W1l.T + b1 + x@W1r.T)   (bf16, in place over xb)
    sage_aggr<<<aggr_grid, 256, 0, stream>>>(xb, rowptr, sorted, ag);
    sage_gemm<0><<<gemm_grid, 256, 0, stream>>>(ag, xb, wc1, b1, (void*)hb);
    // layer 2: out = normalize(aggr@W2l.T + b2 + h@W2r.T)  (f32, norm fused)
    sage_aggr<<<aggr_grid, 256, 0, stream>>>(hb, rowptr, sorted, ag);
    sage_gemm<1><<<gemm_grid, 256, 0, stream>>>(ag, hb, wc2, b2, d_out);
}